// Round 9
// baseline (417.547 us; speedup 1.0000x reference)
//
#include <hip/hip_runtime.h>
#include <hip/hip_bf16.h>

typedef unsigned short ushort_t;
typedef unsigned int uint_t;
typedef unsigned char uchar_t;

typedef __attribute__((ext_vector_type(8))) short bf16x8;
typedef __attribute__((ext_vector_type(4))) float f32x4;
typedef __attribute__((ext_vector_type(2))) float f32x2;

__device__ __forceinline__ float bf2f(ushort_t u) {
    union { uint_t i; float f; } v; v.i = ((uint_t)u) << 16; return v.f;
}
__device__ __forceinline__ ushort_t f2bf(float f) {
    __hip_bfloat16 h = __float2bfloat16(f);
    ushort_t u; __builtin_memcpy(&u, &h, 2); return u;
}
__device__ __forceinline__ uchar_t f2fp8(float v) {
    int p = __builtin_amdgcn_cvt_pk_fp8_f32(v, v, 0, false);
    return (uchar_t)(p & 0xff);
}
__device__ __forceinline__ float leaky(float v) { return (v > 0.f) ? v : 0.2f * v; }

#define PO_AS1 0
#define PO_AD1 512
#define PO_B1  1024
#define PO_W2  1536
#define PO_AS2 6656
#define PO_AD2 6666
#define PO_B2  6676
#define PTOT   6686

// block-local fp32-vs-bf16 probe on x (first 4096 ushorts).
__device__ __forceinline__ bool detect_fp32_local(const ushort_t* __restrict__ xa) {
    __shared__ int cnt;
    if (threadIdx.x == 0) cnt = 0;
    __syncthreads();
    int bad = 0;
    for (int i = threadIdx.x; i < 4096; i += 256) {
        float v = bf2f(xa[i]);
        if (!(fabsf(v) < 1e4f)) bad++;
    }
    if (bad) atomicAdd(&cnt, bad);
    __syncthreads();
    return cnt >= 16;
}

// ---- prep: W1 transpose + param normalize + deg zero ----
__global__ __launch_bounds__(256) void k_prep(const void* __restrict__ x,
                                              const void* __restrict__ W1,
                                              const void* as1, const void* ad1,
                                              const void* b1, const void* W2,
                                              const void* as2, const void* ad2,
                                              const void* b2,
                                              ushort_t* __restrict__ W1t,
                                              float* __restrict__ prm,
                                              int* __restrict__ deg, int N) {
    int b = blockIdx.x, t = threadIdx.x;
    if (b < 283) {
        bool isf = detect_fp32_local((const ushort_t*)x);
        if (b < 256) {
            int idx = b * 256 + t;
            int n = idx & 511, k = idx >> 9;
            float v = isf ? ((const float*)W1)[k * 512 + n]
                          : bf2f(((const ushort_t*)W1)[k * 512 + n]);
            W1t[n * 128 + k] = f2bf(v);
        } else {
            int i = (b - 256) * 256 + t;
            if (i < PTOT) {
                const void* src; int off;
                if (i < 512)       { src = as1; off = i; }
                else if (i < 1024) { src = ad1; off = i - 512; }
                else if (i < 1536) { src = b1;  off = i - 1024; }
                else if (i < 6656) { src = W2;  off = i - 1536; }
                else if (i < 6666) { src = as2; off = i - 6656; }
                else if (i < 6676) { src = ad2; off = i - 6666; }
                else               { src = b2;  off = i - 6676; }
                prm[i] = isf ? ((const float*)src)[off] : bf2f(((const ushort_t*)src)[off]);
            }
        }
    } else {
        int i = (b - 283) * 256 + t;
        if (i < N) deg[i] = 0;
    }
}

// ------ GEMM1 + layer-1 logits: h1(fp8) = x @ W1, bf16 MFMA ------
__global__ __launch_bounds__(256) void k_gemm1(const void* __restrict__ xraw,
                                               const ushort_t* __restrict__ w1t,
                                               const float* __restrict__ prm,
                                               uchar_t* __restrict__ h1,
                                               float* __restrict__ asrcf,
                                               float* __restrict__ adstf) {
    int t = threadIdx.x;
    int wave = t >> 6, lane = t & 63;
    int m0 = blockIdx.x * 16;
    bool isf = detect_fp32_local((const ushort_t*)xraw);
    __shared__ ushort_t sA[16 * 128];
    {
        ushort_t tmp[8];
        if (isf) {
            const float4* x4 = (const float4*)((const float*)xraw + (size_t)m0 * 128);
            float4 f0 = x4[2 * t], f1 = x4[2 * t + 1];
            tmp[0] = f2bf(f0.x); tmp[1] = f2bf(f0.y); tmp[2] = f2bf(f0.z); tmp[3] = f2bf(f0.w);
            tmp[4] = f2bf(f1.x); tmp[5] = f2bf(f1.y); tmp[6] = f2bf(f1.z); tmp[7] = f2bf(f1.w);
        } else {
            const uint4* x4 = (const uint4*)((const ushort_t*)xraw + (size_t)m0 * 128);
            uint4 u = x4[t];
            __builtin_memcpy(tmp, &u, 16);
        }
        *reinterpret_cast<uint4*>(&sA[t * 8]) = *reinterpret_cast<uint4*>(tmp);
    }
    __syncthreads();
    int mr = lane & 15, quad = lane >> 4;
    int n0 = wave * 128;
    f32x4 acc[8];
#pragma unroll
    for (int ct = 0; ct < 8; ++ct) acc[ct] = {0.f, 0.f, 0.f, 0.f};
#pragma unroll
    for (int kk = 0; kk < 4; ++kk) {
        bf16x8 a = *reinterpret_cast<const bf16x8*>(&sA[mr * 128 + quad * 8 + kk * 32]);
#pragma unroll
        for (int ct = 0; ct < 8; ++ct) {
            bf16x8 bb = *reinterpret_cast<const bf16x8*>(
                &w1t[(size_t)(n0 + ct * 16 + mr) * 128 + quad * 8 + kk * 32]);
            acc[ct] = __builtin_amdgcn_mfma_f32_16x16x32_bf16(a, bb, acc[ct], 0, 0, 0);
        }
    }
    int col = lane & 15;
#pragma unroll
    for (int hh = 0; hh < 2; ++hh) {
        float Ss[4] = {0.f, 0.f, 0.f, 0.f}, Dd[4] = {0.f, 0.f, 0.f, 0.f};
#pragma unroll
        for (int c4 = 0; c4 < 4; ++c4) {
            int ct = hh * 4 + c4;
            int abscol = n0 + ct * 16 + col;
            float asv = prm[PO_AS1 + abscol];
            float adv = prm[PO_AD1 + abscol];
            float ps[4], pd[4];
#pragma unroll
            for (int r = 0; r < 4; ++r) {
                h1[(size_t)(m0 + quad * 4 + r) * 512 + abscol] = f2fp8(acc[ct][r]);
                ps[r] = acc[ct][r] * asv;
                pd[r] = acc[ct][r] * adv;
            }
#pragma unroll
            for (int off = 1; off <= 8; off <<= 1) {
#pragma unroll
                for (int r = 0; r < 4; ++r) {
                    ps[r] += __shfl_xor(ps[r], off, 64);
                    pd[r] += __shfl_xor(pd[r], off, 64);
                }
            }
#pragma unroll
            for (int r = 0; r < 4; ++r) { Ss[r] += ps[r]; Dd[r] += pd[r]; }
        }
        if (col == 0) {
            int head = 2 * wave + hh;
#pragma unroll
            for (int r = 0; r < 4; ++r) {
                asrcf[(m0 + quad * 4 + r) * 8 + head] = Ss[r];
                adstf[(m0 + quad * 4 + r) * 8 + head] = Dd[r];
            }
        }
    }
}

// ---------------- CSR build ----------------
__global__ void k_hist(const int* __restrict__ ei, int* __restrict__ deg, int E, int Etot) {
    int e = blockIdx.x * 256 + threadIdx.x;
    if (e >= Etot) return;
    int dst = (e < E) ? ei[E + e] : (e - E);
    atomicAdd(&deg[dst], 1);
}

__global__ __launch_bounds__(1024) void k_scan1(const int* __restrict__ deg,
                                                int* __restrict__ rowptr,
                                                int* __restrict__ bsum, int N) {
    int b = blockIdx.x, t = threadIdx.x;
    int lane = t & 63, wv = t >> 6;
    int i = b * 1000 + t;
    int v = (t < 1000 && i < N) ? deg[i] : 0;
    int sv = v;
#pragma unroll
    for (int off = 1; off < 64; off <<= 1) {
        int u = __shfl_up(sv, off, 64);
        if (lane >= off) sv += u;
    }
    __shared__ int wsum[16], woff[16];
    if (lane == 63) wsum[wv] = sv;
    __syncthreads();
    if (t < 16) {
        int s = wsum[t], sc = s;
#pragma unroll
        for (int off = 1; off < 16; off <<= 1) {
            int u = __shfl_up(sc, off, 16);
            if ((t & 15) >= off) sc += u;
        }
        woff[t] = sc - s;
    }
    __syncthreads();
    int inc = sv + woff[wv];
    if (t < 1000 && i < N) rowptr[i + 1] = inc;
    if (t == 1023) bsum[b] = inc;
}

__global__ __launch_bounds__(256) void k_scan3(const int* __restrict__ deg,
                                               const int* __restrict__ bsum,
                                               int* __restrict__ rowptr,
                                               int* __restrict__ cursor, int N) {
    __shared__ int sboffs[20];
    int t = threadIdx.x;
    if (t < 64) {
        int v = (t < 20) ? bsum[t] : 0;
        int sc = v;
#pragma unroll
        for (int off = 1; off < 32; off <<= 1) {
            int u = __shfl_up(sc, off, 64);
            if (t >= off) sc += u;
        }
        if (t < 20) sboffs[t] = sc - v;
    }
    __syncthreads();
    int i = blockIdx.x * 256 + t;
    if (i >= N) return;
    int r = rowptr[i + 1] + sboffs[i / 1000];
    rowptr[i + 1] = r;
    cursor[i] = r - deg[i];
    if (i == 0) rowptr[0] = 0;
}

__global__ void k_scatter(const int* __restrict__ ei, int* __restrict__ cursor,
                          int* __restrict__ csr_src, int* __restrict__ csr_dst,
                          int E, int Etot) {
    int e = blockIdx.x * 256 + threadIdx.x;
    if (e >= Etot) return;
    int src, dst;
    if (e < E) { src = ei[e]; dst = ei[E + e]; } else { src = dst = e - E; }
    int pos = atomicAdd(&cursor[dst], 1);
    csr_src[pos] = src;
    csr_dst[pos] = dst;
}

// ---- per-(edge,head) softmax weights, layer 1 (edge-parallel, coalesced) ----
__global__ __launch_bounds__(256) void k_wts1(const int* __restrict__ csr_src,
                                              const int* __restrict__ csr_dst,
                                              const float* __restrict__ asrcf,
                                              const float* __restrict__ adstf,
                                              float* __restrict__ wts1, int Etot) {
    int idx = blockIdx.x * 256 + threadIdx.x;
    if (idx >= Etot * 8) return;
    int e = idx >> 3, h = idx & 7;
    int s = csr_src[e], d = csr_dst[e];
    wts1[idx] = __expf(leaky(asrcf[s * 8 + h] + adstf[d * 8 + h]));
}

// --- layer-1 agg, XCD-SLICED: slice = 128 channels (2.56 MB fp8, fits 4MB L2).
// blockIdx%8 -> XCD (heuristic); slice = (blockIdx%8)>>1 so each slice owns 2 XCDs.
// Wave per node; 4 edges per iter (16 lanes x 8B = 128B slice-row per edge).
// Slice partials of fused layer-2 linear combined via atomicAdd into h2.
__global__ __launch_bounds__(256) void k_agg1(const uchar_t* __restrict__ h1,
                                              const float* __restrict__ wts1,
                                              const int* __restrict__ rowptr,
                                              const int* __restrict__ csr_src,
                                              const float* __restrict__ prm,
                                              float* __restrict__ h2) {
    int b = blockIdx.x;
    int slice = (b & 7) >> 1;
    int sub = ((b >> 3) << 1) | (b & 1);      // 0..4999
    int wave = threadIdx.x >> 6, lane = threadIdx.x & 63;
    int n = sub * 4 + wave;
    int es = lane >> 4;                        // edge sublane 0..3
    int cl = lane & 15;                        // channel lane 0..15
    int cb = slice * 128 + cl * 8;             // absolute channel base
    int hh = slice * 2 + (cl >> 3);            // head of my channels
    int start = rowptr[n], end = rowptr[n + 1];
    int deg = end - start;
    float a0 = 0.f, a1 = 0.f, a2 = 0.f, a3 = 0.f, a4 = 0.f, a5 = 0.f, a6 = 0.f, a7 = 0.f;
    float den = 0.f;
    for (int base = 0; base < deg; base += 64) {
        int m = min(64, deg - base);
        int sIdx = csr_src[start + base + min(lane, m - 1)];
        for (int g = 0; g < m; g += 8) {
            int s[2]; float w[2]; uint2 p[2];
#pragma unroll
            for (int j = 0; j < 2; ++j) {
                int idx = g + 4 * j + es;
                int ce = min(idx, m - 1);
                s[j] = __shfl(sIdx, ce, 64);
                float ww = wts1[(size_t)(start + base + ce) * 8 + hh];
                w[j] = (idx < m) ? ww : 0.f;
            }
#pragma unroll
            for (int j = 0; j < 2; ++j)
                p[j] = *reinterpret_cast<const uint2*>(&h1[(size_t)s[j] * 512 + cb]);
#pragma unroll
            for (int j = 0; j < 2; ++j) {
                float we = w[j];
                den += we;
                f32x2 q0 = __builtin_amdgcn_cvt_pk_f32_fp8((int)p[j].x, false);
                f32x2 q1 = __builtin_amdgcn_cvt_pk_f32_fp8((int)p[j].x, true);
                f32x2 q2 = __builtin_amdgcn_cvt_pk_f32_fp8((int)p[j].y, false);
                f32x2 q3 = __builtin_amdgcn_cvt_pk_f32_fp8((int)p[j].y, true);
                a0 += we * q0.x; a1 += we * q0.y;
                a2 += we * q1.x; a3 += we * q1.y;
                a4 += we * q2.x; a5 += we * q2.y;
                a6 += we * q3.x; a7 += we * q3.y;
            }
        }
    }
    // combine across edge sublanes (xor 16, 32): every lane gets full sums
    float a[8] = {a0, a1, a2, a3, a4, a5, a6, a7};
#pragma unroll
    for (int off = 16; off <= 32; off <<= 1) {
        den += __shfl_xor(den, off, 64);
#pragma unroll
        for (int j = 0; j < 8; ++j) a[j] += __shfl_xor(a[j], off, 64);
    }
    float inv = 1.f / (den + 1e-16f);
    float p2[10];
#pragma unroll
    for (int c = 0; c < 10; ++c) p2[c] = 0.f;
#pragma unroll
    for (int j = 0; j < 8; ++j) {
        float rv = a[j] * inv + prm[PO_B1 + cb + j];
        rv = (rv > 0.f) ? rv : expm1f(rv);    // ELU
#pragma unroll
        for (int c = 0; c < 10; ++c)
            p2[c] += rv * prm[PO_W2 + (cb + j) * 10 + c];
    }
    // reduce over the 16 channel lanes
#pragma unroll
    for (int off = 1; off <= 8; off <<= 1)
#pragma unroll
        for (int c = 0; c < 10; ++c)
            p2[c] += __shfl_xor(p2[c], off, 64);
    if (lane == 0)
#pragma unroll
        for (int c = 0; c < 10; ++c)
            atomicAdd(&h2[n * 10 + c], p2[c]);
}

// ---- per-node layer-2 logits + bf16-packed h2 (padded to 32 B rows) ----
__global__ __launch_bounds__(256) void k_logits2(const float* __restrict__ h2,
                                                 const float* __restrict__ prm,
                                                 ushort_t* __restrict__ h2b,
                                                 float* __restrict__ asrc2f,
                                                 float* __restrict__ adst2f, int N) {
    int n = blockIdx.x * 256 + threadIdx.x;
    if (n >= N) return;
    float as = 0.f, ad = 0.f;
#pragma unroll
    for (int c = 0; c < 10; ++c) {
        float v = h2[n * 10 + c];
        h2b[n * 16 + c] = f2bf(v);
        as += v * prm[PO_AS2 + c];
        ad += v * prm[PO_AD2 + c];
    }
    asrc2f[n] = as; adst2f[n] = ad;
}

// ---- per-edge softmax weights, layer 2 ----
__global__ __launch_bounds__(256) void k_wts2(const int* __restrict__ csr_src,
                                              const int* __restrict__ csr_dst,
                                              const float* __restrict__ asrc2f,
                                              const float* __restrict__ adst2f,
                                              float* __restrict__ wts2, int Etot) {
    int e = blockIdx.x * 256 + threadIdx.x;
    if (e >= Etot) return;
    wts2[e] = __expf(leaky(asrc2f[csr_src[e]] + adst2f[csr_dst[e]]));
}

// ------- layer-2 aggregation: wave per dst, lane per edge, bf16 h2 (2 loads) -------
__global__ __launch_bounds__(256) void k_agg2(const ushort_t* __restrict__ h2b,
                                              const float* __restrict__ wts2,
                                              const int* __restrict__ rowptr,
                                              const int* __restrict__ csr_src,
                                              const float* __restrict__ prm,
                                              float* __restrict__ out2) {
    int n = blockIdx.x * 4 + (threadIdx.x >> 6);
    int l = threadIdx.x & 63;
    int start = rowptr[n], end = rowptr[n + 1];
    float den = 0.f;
    float oc[10];
#pragma unroll
    for (int c = 0; c < 10; ++c) oc[c] = 0.f;
    for (int base = start; base < end; base += 64) {
        int e = base + l;
        int ce = min(e, end - 1);
        float w = wts2[ce];
        if (e >= end) w = 0.f;
        int s = csr_src[ce];
        uint4 u0 = *reinterpret_cast<const uint4*>(&h2b[s * 16]);
        uint_t u1 = *reinterpret_cast<const uint_t*>(&h2b[s * 16 + 8]);
        den += w;
        oc[0] += w * bf2f((ushort_t)(u0.x & 0xffff)); oc[1] += w * bf2f((ushort_t)(u0.x >> 16));
        oc[2] += w * bf2f((ushort_t)(u0.y & 0xffff)); oc[3] += w * bf2f((ushort_t)(u0.y >> 16));
        oc[4] += w * bf2f((ushort_t)(u0.z & 0xffff)); oc[5] += w * bf2f((ushort_t)(u0.z >> 16));
        oc[6] += w * bf2f((ushort_t)(u0.w & 0xffff)); oc[7] += w * bf2f((ushort_t)(u0.w >> 16));
        oc[8] += w * bf2f((ushort_t)(u1 & 0xffff));   oc[9] += w * bf2f((ushort_t)(u1 >> 16));
    }
#pragma unroll
    for (int off = 32; off; off >>= 1) {
        den += __shfl_xor(den, off, 64);
#pragma unroll
        for (int c = 0; c < 10; ++c) oc[c] += __shfl_xor(oc[c], off, 64);
    }
    if (l == 0) {
        float inv = 1.f / (den + 1e-16f);
        for (int c = 0; c < 10; ++c) out2[n * 10 + c] = oc[c] * inv + prm[PO_B2 + c];
    }
}

// ---------------- per-graph mean pool ----------------
__global__ __launch_bounds__(256) void k_pool(const float* __restrict__ out2,
                                              const int* __restrict__ batch,
                                              const void* __restrict__ x,
                                              void* __restrict__ dout, int N) {
    bool isf = detect_fp32_local((const ushort_t*)x);
    int g = blockIdx.x, t = threadIdx.x;
    __shared__ int s_lo, s_hi;
    __shared__ float sm[256];
    if (t == 0) {
        int lo = 0, hi = N;
        while (lo < hi) { int mid = (lo + hi) >> 1; if (batch[mid] < g) lo = mid + 1; else hi = mid; }
        s_lo = lo;
        int lo2 = lo, hi2 = N;
        while (lo2 < hi2) { int mid = (lo2 + hi2) >> 1; if (batch[mid] < g + 1) lo2 = mid + 1; else hi2 = mid; }
        s_hi = lo2;
    }
    __syncthreads();
    int lo = s_lo, hi = s_hi;
    float acc[10];
#pragma unroll
    for (int c = 0; c < 10; ++c) acc[c] = 0.f;
    for (int i = lo + t; i < hi; i += 256)
#pragma unroll
        for (int c = 0; c < 10; ++c) acc[c] += out2[i * 10 + c];
    float cnt = (float)((hi - lo) > 0 ? (hi - lo) : 1);
    for (int c = 0; c < 10; ++c) {
        sm[t] = acc[c]; __syncthreads();
        for (int off = 128; off; off >>= 1) {
            if (t < off) sm[t] += sm[t + off];
            __syncthreads();
        }
        if (t == 0) {
            float r = sm[0] / cnt;
            if (isf) ((float*)dout)[g * 10 + c] = r;
            else     ((ushort_t*)dout)[g * 10 + c] = f2bf(r);
        }
        __syncthreads();
    }
}

extern "C" void kernel_launch(void* const* d_in, const int* in_sizes, int n_in,
                              void* d_out, int out_size, void* d_ws, size_t ws_size,
                              hipStream_t stream) {
    const void* x   = d_in[0];
    const int* ei   = (const int*)d_in[1];
    const int* batch= (const int*)d_in[2];
    const void* W1  = d_in[3];
    const void* as1 = d_in[4];
    const void* ad1 = d_in[5];
    const void* b1  = d_in[6];
    const void* W2  = d_in[7];
    const void* as2 = d_in[8];
    const void* ad2 = d_in[9];
    const void* b2  = d_in[10];

    constexpr int N = 20000, E = 320000, Etot = E + N;

    char* p = (char*)d_ws;
    auto alloc = [&](size_t bytes) {
        char* r = p; p += (bytes + 255) & ~(size_t)255; return r;
    };
    float* prm      = (float*)alloc((size_t)PTOT * 4);
    ushort_t* w1t   = (ushort_t*)alloc(512 * 128 * 2);
    uchar_t* h1     = (uchar_t*)alloc((size_t)N * 512);           // 10.24 MB fp8
    float* asrc1f   = (float*)alloc((size_t)N * 8 * 4);
    float* adst1f   = (float*)alloc((size_t)N * 8 * 4);
    float* asrc2f   = (float*)alloc((size_t)N * 4);
    float* adst2f   = (float*)alloc((size_t)N * 4);
    float* h2       = (float*)alloc((size_t)N * 10 * 4);
    ushort_t* h2b   = (ushort_t*)alloc((size_t)N * 16 * 2);      // bf16, 32B rows
    float* out2     = (float*)alloc((size_t)N * 10 * 4);
    int* deg        = (int*)alloc((size_t)N * 4);
    int* rowptr     = (int*)alloc((size_t)(N + 1) * 4);
    int* cursor     = (int*)alloc((size_t)N * 4);
    int* csr_src    = (int*)alloc((size_t)Etot * 4);
    int* csr_dst    = (int*)alloc((size_t)Etot * 4);
    float* wts1     = (float*)alloc((size_t)Etot * 8 * 4);       // 10.88 MB
    float* wts2     = (float*)alloc((size_t)Etot * 4);
    int* bsum       = (int*)alloc(32 * 4);
    // total ~30 MB

    hipMemsetAsync(h2, 0, (size_t)N * 10 * 4, stream);

    k_prep<<<362, 256, 0, stream>>>(x, W1, as1, ad1, b1, W2, as2, ad2, b2,
                                    w1t, prm, deg, N);
    k_gemm1<<<1250, 256, 0, stream>>>(x, w1t, prm, h1, asrc1f, adst1f);
    k_hist<<<(Etot + 255) / 256, 256, 0, stream>>>(ei, deg, E, Etot);
    k_scan1<<<20, 1024, 0, stream>>>(deg, rowptr, bsum, N);
    k_scan3<<<(N + 255) / 256, 256, 0, stream>>>(deg, bsum, rowptr, cursor, N);
    k_scatter<<<(Etot + 255) / 256, 256, 0, stream>>>(ei, cursor, csr_src, csr_dst, E, Etot);
    k_wts1<<<(Etot * 8 + 255) / 256, 256, 0, stream>>>(csr_src, csr_dst, asrc1f, adst1f, wts1, Etot);
    k_agg1<<<N, 256, 0, stream>>>(h1, wts1, rowptr, csr_src, prm, h2);
    k_logits2<<<(N + 255) / 256, 256, 0, stream>>>(h2, prm, h2b, asrc2f, adst2f, N);
    k_wts2<<<(Etot + 255) / 256, 256, 0, stream>>>(csr_src, csr_dst, asrc2f, adst2f, wts2, Etot);
    k_agg2<<<N / 4, 256, 0, stream>>>(h2b, wts2, rowptr, csr_src, prm, out2);
    k_pool<<<64, 256, 0, stream>>>(out2, batch, x, d_out, N);
}